// Round 1
// baseline (519.314 us; speedup 1.0000x reference)
//
#include <hip/hip_runtime.h>
#include <hip/hip_bf16.h>

// Mixtral sparse MoE: T=4096 tokens, D=1024, F=3584, E=8, top-2.
// Pipeline: route -> scan(pad offsets) -> scatter(token lists) -> cvt x->bf16
//           -> GEMM1 (gathered x @ [w1;w3]^T, fused silu*mul -> h bf16)
//           -> GEMM2 (h @ w2^T, scale by routing weight, atomicAdd into out)

#define T_TOK 4096
#define DIM   1024
#define FF    3584
#define NE    8
#define BM    128
#define CAP   (T_TOK*2 + NE*BM)   // 9216 padded pair rows

using f32x4 = __attribute__((ext_vector_type(4))) float;
using s16x8 = __attribute__((ext_vector_type(8))) short;

__device__ __forceinline__ ushort f2b(float f) {
    __hip_bfloat16 b = __float2bfloat16(f);   // round-to-nearest-even
    ushort u; __builtin_memcpy(&u, &b, 2); return u;
}

// ---------------- routing: one wave per token ----------------
__global__ __launch_bounds__(256)
void k_route(const float* __restrict__ x, const float* __restrict__ gw,
             int* __restrict__ topi, float* __restrict__ topw, int* __restrict__ counts)
{
    __shared__ float gws[NE*DIM];                       // 32 KB
    const int tid = threadIdx.x;
    for (int i = tid; i < NE*DIM/4; i += 256)
        ((float4*)gws)[i] = ((const float4*)gw)[i];
    __syncthreads();

    const int lane = tid & 63, wid = tid >> 6;
    const int t = blockIdx.x*4 + wid;

    float4 xr[4];
    const float4* xrow = (const float4*)(x + (size_t)t*DIM) + lane*4;
    #pragma unroll
    for (int i = 0; i < 4; ++i) xr[i] = xrow[i];

    float lg[NE];
    #pragma unroll
    for (int e = 0; e < NE; ++e) {
        const float4* g4 = (const float4*)(gws + e*DIM) + lane*4;
        float s = 0.f;
        #pragma unroll
        for (int i = 0; i < 4; ++i) {
            float4 g = g4[i];
            s += xr[i].x*g.x + xr[i].y*g.y + xr[i].z*g.z + xr[i].w*g.w;
        }
        #pragma unroll
        for (int off = 32; off; off >>= 1) s += __shfl_xor(s, off);
        lg[e] = s;
    }
    if (lane == 0) {
        float b1 = -1e30f, b2 = -1e30f; int i1 = 0, i2 = 0;
        #pragma unroll
        for (int e = 0; e < NE; ++e) {
            float v = lg[e];
            if (v > b1)      { b2 = b1; i2 = i1; b1 = v; i1 = e; }
            else if (v > b2) { b2 = v; i2 = e; }
        }
        // softmax denom cancels in top-k renorm: w = exp(l)/sum(exp(top l))
        float p2 = __expf(b2 - b1);
        float inv = 1.f / (1.f + p2);
        topi[2*t]   = i1; topi[2*t+1] = i2;
        topw[2*t]   = inv; topw[2*t+1] = p2*inv;
        atomicAdd(&counts[i1], 1); atomicAdd(&counts[i2], 1);
    }
}

// ---------------- scan: padded per-expert offsets + fill rowTok=-1 -----------
__global__ void k_scan(const int* __restrict__ counts, int* __restrict__ offs,
                       int* __restrict__ rowTok)
{
    if (threadIdx.x == 0) {
        int acc = 0; offs[0] = 0;
        for (int e = 0; e < NE; ++e) {
            int p = (counts[e] + BM - 1) & ~(BM - 1);
            acc += p; offs[e+1] = acc;
        }
    }
    for (int i = threadIdx.x; i < CAP; i += blockDim.x) rowTok[i] = -1;
}

// ---------------- scatter tokens into per-expert row lists ----------------
__global__ __launch_bounds__(256)
void k_scatter(const int* __restrict__ topi, const float* __restrict__ topw,
               const int* __restrict__ offs, int* __restrict__ cursor,
               int* __restrict__ rowTok, float* __restrict__ rowW)
{
    int t = blockIdx.x*256 + threadIdx.x;
    #pragma unroll
    for (int j = 0; j < 2; ++j) {
        int e = topi[2*t + j];
        int pos = offs[e] + atomicAdd(&cursor[e], 1);
        rowTok[pos] = t;
        rowW[pos] = topw[2*t + j];
    }
}

// ---------------- x fp32 -> bf16 ----------------
__global__ __launch_bounds__(256)
void k_cvt(const float* __restrict__ x, ushort* __restrict__ xb)
{
    size_t i = (size_t)blockIdx.x*256 + threadIdx.x;    // 8 elems each
    const float4* src = (const float4*)x + i*2;
    float4 v0 = src[0], v1 = src[1];
    uint4 o;
    o.x = f2b(v0.x) | ((uint)f2b(v0.y) << 16);
    o.y = f2b(v0.z) | ((uint)f2b(v0.w) << 16);
    o.z = f2b(v1.x) | ((uint)f2b(v1.y) << 16);
    o.w = f2b(v1.z) | ((uint)f2b(v1.w) << 16);
    ((uint4*)xb)[i] = o;
}

// ---------------- GEMM1: h = silu(xg @ w1^T) * (xg @ w3^T) ----------------
// Tile: 128 rows x 64 f-cols, BK=64. B tile stacks w1(64 rows)+w3(64 rows).
// 4 waves: wr=M-half (64 rows), wc=F-half (32 cols). Double-buffered LDS,
// reg-staged (fp32->bf16 cvt for weights), XOR swizzle (row&7)<<4.
__global__ __launch_bounds__(256, 2)
void k_gemm1(const ushort* __restrict__ xb,
             const float* __restrict__ w1g, const float* __restrict__ w3g,
             const int* __restrict__ offs, const int* __restrict__ rowTok,
             ushort* __restrict__ hout)
{
    __shared__ __align__(16) ushort As[2][128*64];   // 16 KB each
    __shared__ __align__(16) ushort Bs[2][128*64];   // 16 KB each
    const int rowStart = blockIdx.y * BM;
    if (rowStart >= offs[8]) return;
    int e = 0;
    #pragma unroll
    for (int k = 1; k < NE; ++k) if (rowStart >= offs[k]) e = k;

    const int fc = blockIdx.x * 64;
    const float* __restrict__ W1 = w1g + ((size_t)e*FF + fc)*DIM;
    const float* __restrict__ W3 = w3g + ((size_t)e*FF + fc)*DIM;

    const int tid = threadIdx.x;
    const int lane = tid & 63, wid = tid >> 6;
    const int wr = wid >> 1, wc = wid & 1;
    const int lo = lane & 15, hi = lane >> 4;

    const int aRowB = tid >> 3;   // 0..31, A row within 32-row group
    const int aC8   = tid & 7;    // 16B chunk (8 bf16)
    const int bRowB = tid >> 4;   // 0..15
    const int bC4   = tid & 15;   // float4 chunk

    int atok[4];
    #pragma unroll
    for (int p = 0; p < 4; ++p) atok[p] = rowTok[rowStart + p*32 + aRowB];

    uint4  ar[4];
    float4 br[8];

    auto loadT = [&](int kt) {
        const int k0 = kt * 64;
        #pragma unroll
        for (int p = 0; p < 4; ++p) {
            if (atok[p] >= 0)
                ar[p] = *(const uint4*)(xb + (size_t)atok[p]*DIM + k0 + aC8*8);
            else
                ar[p] = uint4{0u,0u,0u,0u};
        }
        #pragma unroll
        for (int p = 0; p < 8; ++p) {
            int r = p*16 + bRowB;
            const float* src = (p < 4) ? (W1 + (size_t)r*DIM) : (W3 + (size_t)(r-64)*DIM);
            br[p] = *(const float4*)(src + k0 + bC4*4);
        }
    };
    auto storeT = [&](int buf) {
        char* Ab = (char*)As[buf];
        #pragma unroll
        for (int p = 0; p < 4; ++p) {
            int r = p*32 + aRowB;
            *(uint4*)(Ab + r*128 + ((aC8*16) ^ ((r&7)<<4))) = ar[p];
        }
        char* Bb = (char*)Bs[buf];
        #pragma unroll
        for (int p = 0; p < 8; ++p) {
            int r = p*16 + bRowB;
            ushort4 c;
            c.x = f2b(br[p].x); c.y = f2b(br[p].y);
            c.z = f2b(br[p].z); c.w = f2b(br[p].w);
            *(ushort4*)(Bb + r*128 + ((bC4*8) ^ ((r&7)<<4))) = c;
        }
    };

    f32x4 acc1[4][2], acc3[4][2];
    #pragma unroll
    for (int m = 0; m < 4; ++m)
        #pragma unroll
        for (int n = 0; n < 2; ++n) { acc1[m][n] = (f32x4)(0.f); acc3[m][n] = (f32x4)(0.f); }

    auto compute = [&](int buf) {
        char* Ab = (char*)As[buf];
        char* Bb = (char*)Bs[buf];
        #pragma unroll
        for (int kk = 0; kk < 2; ++kk) {
            s16x8 a[4], b1[2], b3[2];
            #pragma unroll
            for (int m = 0; m < 4; ++m) {
                int r = wr*64 + m*16 + lo;
                a[m] = *(const s16x8*)(Ab + r*128 + ((kk*64 + hi*16) ^ ((r&7)<<4)));
            }
            #pragma unroll
            for (int n = 0; n < 2; ++n) {
                int r1 = wc*32 + n*16 + lo;
                b1[n] = *(const s16x8*)(Bb + r1*128 + ((kk*64 + hi*16) ^ ((r1&7)<<4)));
                int r3 = r1 + 64;
                b3[n] = *(const s16x8*)(Bb + r3*128 + ((kk*64 + hi*16) ^ ((r3&7)<<4)));
            }
            #pragma unroll
            for (int m = 0; m < 4; ++m)
                #pragma unroll
                for (int n = 0; n < 2; ++n) {
                    acc1[m][n] = __builtin_amdgcn_mfma_f32_16x16x32_bf16(a[m], b1[n], acc1[m][n], 0, 0, 0);
                    acc3[m][n] = __builtin_amdgcn_mfma_f32_16x16x32_bf16(a[m], b3[n], acc3[m][n], 0, 0, 0);
                }
        }
    };

    loadT(0); storeT(0); __syncthreads();
    int cur = 0;
    const int NK = DIM/64;   // 16
    for (int kt = 0; kt < NK; ++kt) {
        bool more = (kt + 1 < NK);
        if (more) loadT(kt + 1);
        compute(cur);
        if (more) storeT(cur ^ 1);
        __syncthreads();
        cur ^= 1;
    }

    // epilogue: silu(acc1)*acc3 -> h (bf16) by padded row (no gather in GEMM2)
    #pragma unroll
    for (int m = 0; m < 4; ++m)
        #pragma unroll
        for (int n = 0; n < 2; ++n) {
            f32x4 v1 = acc1[m][n], v3 = acc3[m][n];
            int col = fc + wc*32 + n*16 + lo;
            #pragma unroll
            for (int j = 0; j < 4; ++j) {
                int row = wr*64 + m*16 + hi*4 + j;
                float s = v1[j];
                float val = (s / (1.f + __expf(-s))) * v3[j];
                hout[(size_t)(rowStart + row)*FF + col] = f2b(val);
            }
        }
}

// ---------------- GEMM2: out[tok] += rw * (h @ w2^T) ----------------
// Tile: 128 rows x 128 d-cols, BK=64 over F=3584. 4 waves 2x2, 64x64 each.
__global__ __launch_bounds__(256, 2)
void k_gemm2(const ushort* __restrict__ h,
             const float* __restrict__ w2g,
             const int* __restrict__ offs, const int* __restrict__ rowTok,
             const float* __restrict__ rowW, float* __restrict__ out)
{
    __shared__ __align__(16) ushort As[2][128*64];
    __shared__ __align__(16) ushort Bs[2][128*64];
    const int rowStart = blockIdx.y * BM;
    if (rowStart >= offs[8]) return;
    int e = 0;
    #pragma unroll
    for (int k = 1; k < NE; ++k) if (rowStart >= offs[k]) e = k;

    const int dc = blockIdx.x * 128;
    const float* __restrict__ W2 = w2g + ((size_t)e*DIM + dc)*FF;

    const int tid = threadIdx.x;
    const int lane = tid & 63, wid = tid >> 6;
    const int wr = wid >> 1, wc = wid & 1;
    const int lo = lane & 15, hi = lane >> 4;

    const int aRowB = tid >> 3;
    const int aC8   = tid & 7;
    const int bRowB = tid >> 4;
    const int bC4   = tid & 15;

    uint4  ar[4];
    float4 br[8];

    auto loadT = [&](int kt) {
        const int k0 = kt * 64;
        #pragma unroll
        for (int p = 0; p < 4; ++p) {
            int r = p*32 + aRowB;
            ar[p] = *(const uint4*)(h + (size_t)(rowStart + r)*FF + k0 + aC8*8);
        }
        #pragma unroll
        for (int p = 0; p < 8; ++p) {
            int r = p*16 + bRowB;
            br[p] = *(const float4*)(W2 + (size_t)r*FF + k0 + bC4*4);
        }
    };
    auto storeT = [&](int buf) {
        char* Ab = (char*)As[buf];
        #pragma unroll
        for (int p = 0; p < 4; ++p) {
            int r = p*32 + aRowB;
            *(uint4*)(Ab + r*128 + ((aC8*16) ^ ((r&7)<<4))) = ar[p];
        }
        char* Bb = (char*)Bs[buf];
        #pragma unroll
        for (int p = 0; p < 8; ++p) {
            int r = p*16 + bRowB;
            ushort4 c;
            c.x = f2b(br[p].x); c.y = f2b(br[p].y);
            c.z = f2b(br[p].z); c.w = f2b(br[p].w);
            *(ushort4*)(Bb + r*128 + ((bC4*8) ^ ((r&7)<<4))) = c;
        }
    };

    f32x4 acc[4][4];
    #pragma unroll
    for (int m = 0; m < 4; ++m)
        #pragma unroll
        for (int n = 0; n < 4; ++n) acc[m][n] = (f32x4)(0.f);

    auto compute = [&](int buf) {
        char* Ab = (char*)As[buf];
        char* Bb = (char*)Bs[buf];
        #pragma unroll
        for (int kk = 0; kk < 2; ++kk) {
            s16x8 a[4], b[4];
            #pragma unroll
            for (int m = 0; m < 4; ++m) {
                int r = wr*64 + m*16 + lo;
                a[m] = *(const s16x8*)(Ab + r*128 + ((kk*64 + hi*16) ^ ((r&7)<<4)));
            }
            #pragma unroll
            for (int n = 0; n < 4; ++n) {
                int r = wc*64 + n*16 + lo;
                b[n] = *(const s16x8*)(Bb + r*128 + ((kk*64 + hi*16) ^ ((r&7)<<4)));
            }
            #pragma unroll
            for (int m = 0; m < 4; ++m)
                #pragma unroll
                for (int n = 0; n < 4; ++n)
                    acc[m][n] = __builtin_amdgcn_mfma_f32_16x16x32_bf16(a[m], b[n], acc[m][n], 0, 0, 0);
        }
    };

    loadT(0); storeT(0); __syncthreads();
    int cur = 0;
    const int NK = FF/64;   // 56
    for (int kt = 0; kt < NK; ++kt) {
        bool more = (kt + 1 < NK);
        if (more) loadT(kt + 1);
        compute(cur);
        if (more) storeT(cur ^ 1);
        __syncthreads();
        cur ^= 1;
    }

    #pragma unroll
    for (int m = 0; m < 4; ++m)
        #pragma unroll
        for (int j = 0; j < 4; ++j) {
            int prow = rowStart + wr*64 + m*16 + hi*4 + j;
            int tok = rowTok[prow];
            if (tok < 0) continue;
            float w = rowW[prow];
            #pragma unroll
            for (int n = 0; n < 4; ++n) {
                int d = dc + wc*64 + n*16 + lo;
                atomicAdd(&out[(size_t)tok*DIM + d], w * acc[m][n][j]);
            }
        }
}

// ---------------- launch ----------------
extern "C" void kernel_launch(void* const* d_in, const int* in_sizes, int n_in,
                              void* d_out, int out_size, void* d_ws, size_t ws_size,
                              hipStream_t stream)
{
    const float* x  = (const float*)d_in[0];
    const float* gw = (const float*)d_in[1];
    const float* w1 = (const float*)d_in[2];
    const float* w3 = (const float*)d_in[3];
    const float* w2 = (const float*)d_in[4];
    float* out = (float*)d_out;
    char* ws = (char*)d_ws;

    // ws layout (74.6 MB total)
    int*    counts = (int*)ws;                    // 8
    int*    cursor = counts + 8;                  // 8
    int*    offs   = counts + 16;                 // 9
    int*    topi   = (int*)  (ws + 256);                                  // 32 KB
    float*  topw   = (float*)(ws + 256 + (size_t)T_TOK*8);                // 32 KB
    int*    rowTok = (int*)  (ws + 256 + (size_t)T_TOK*16);               // 36 KB
    float*  rowW   = (float*)(ws + 256 + (size_t)T_TOK*16 + (size_t)CAP*4);
    ushort* xb     = (ushort*)(ws + 139520);                              // 8 MB
    ushort* h      = (ushort*)(ws + 8528128);                             // 66 MB

    hipMemsetAsync(ws, 0, 256, stream);                        // counts+cursor
    hipMemsetAsync(d_out, 0, (size_t)T_TOK*DIM*4, stream);

    k_route  <<<T_TOK/4, 256, 0, stream>>>(x, gw, topi, topw, counts);
    k_scan   <<<1, 256, 0, stream>>>(counts, offs, rowTok);
    k_scatter<<<T_TOK/256, 256, 0, stream>>>(topi, topw, offs, cursor, rowTok, rowW);
    k_cvt    <<<(T_TOK*DIM/8)/256, 256, 0, stream>>>(x, xb);
    k_gemm1  <<<dim3(FF/64,  CAP/BM), 256, 0, stream>>>(xb, w1, w3, offs, rowTok, h);
    k_gemm2  <<<dim3(DIM/128, CAP/BM), 256, 0, stream>>>(h, w2, offs, rowTok, rowW, out);
}